// Round 11
// baseline (1981.567 us; speedup 1.0000x reference)
//
#include <hip/hip_runtime.h>
#include <stdint.h>

#define VN   1000000
#define VDIM 256
#define GDIM 256
#define NH   16
#define NG   50000
#define HIDD 128
#define NTILES 15625   // VN / 64
#define TPB   5        // tiles per block; 15625 = 5 * 3125

using bf16x8 = __attribute__((ext_vector_type(8))) __bf16;
using f32x4  = __attribute__((ext_vector_type(4))) float;

__device__ __forceinline__ unsigned short f2bf(float f) {
  __bf16 h = (__bf16)f;
  return __builtin_bit_cast(unsigned short, h);
}
__device__ __forceinline__ bf16x8 pack8v(f32x4 a, f32x4 b) {
  bf16x8 r;
  r[0] = (__bf16)a[0]; r[1] = (__bf16)a[1]; r[2] = (__bf16)a[2]; r[3] = (__bf16)a[3];
  r[4] = (__bf16)b[0]; r[5] = (__bf16)b[1]; r[6] = (__bf16)b[2]; r[7] = (__bf16)b[3];
  return r;
}
__device__ __forceinline__ f32x4 fzero4() { f32x4 z = {0.f, 0.f, 0.f, 0.f}; return z; }

// async global->LDS, 16B/lane; LDS dest = wave-uniform base + lane*16
typedef __attribute__((address_space(1))) const void* gas_t;
typedef __attribute__((address_space(3))) void* las_t;
__device__ __forceinline__ void gld16(const void* g, void* l) {
  __builtin_amdgcn_global_load_lds((gas_t)g, (las_t)l, 16, 0, 0);
}

// raw barrier with counted vmcnt: glds prefetch survives; sched_barrier pins (rule #18)
#define WAITBAR(N) do { \
  asm volatile("s_waitcnt vmcnt(" #N ") lgkmcnt(0)" ::: "memory"); \
  __builtin_amdgcn_sched_barrier(0); \
  __builtin_amdgcn_s_barrier(); \
  __builtin_amdgcn_sched_barrier(0); } while (0)

#define LGKMBAR() do { \
  asm volatile("s_waitcnt lgkmcnt(0)" ::: "memory"); \
  __builtin_amdgcn_sched_barrier(0); \
  __builtin_amdgcn_s_barrier(); \
  __builtin_amdgcn_sched_barrier(0); } while (0)

// ---------------- weight prep: fp32 -> bf16 in MFMA B-fragment order ----------------
// For W[K][N]: frag element idx = ((c*(K/32)+s)*64 + lane)*8 + j  holds W[32s+8*(lane>>4)+j][16c+(lane&15)]
__global__ void k_prep(const float* __restrict__ s1, const float* __restrict__ s2,
                       const float* __restrict__ t1, const float* __restrict__ t2,
                       unsigned short* __restrict__ WB) {
  int t = blockIdx.x * 256 + threadIdx.x;
  const float* W; unsigned short* dst; int K, N, lid;
  if (t < 32768)       { W = s1; dst = WB;          K = 256; N = 128; lid = t; }
  else if (t < 65536)  { W = t1; dst = WB + 32768;  K = 256; N = 128; lid = t - 32768; }
  else if (t < 98304)  { W = t2; dst = WB + 65536;  K = 128; N = 256; lid = t - 65536; }
  else if (t < 100352) { W = s2; dst = WB + 98304;  K = 128; N = 16;  lid = t - 98304; }
  else return;
  int j = lid & 7, l = (lid >> 3) & 63, rem = lid >> 9;
  int KS = K >> 5;
  int s = rem % KS, c = rem / KS;
  int row = 32 * s + 8 * (l >> 4) + j;
  int col = 16 * c + (l & 15);
  dst[lid] = f2bf(W[row * N + col]);
}

// ---------------- zero: out [NG*GDIM] + denom [NG*NH] ----------------
__global__ void k_zero(float* __restrict__ out, float* __restrict__ denom) {
  int i = blockIdx.x * 256 + threadIdx.x;
  float4 z = make_float4(0.f, 0.f, 0.f, 0.f);
  if (i < NG * GDIM / 4) ((float4*)out)[i] = z;
  int j = i - NG * GDIM / 4;
  if (j >= 0 && j < NG * NH / 4) ((float4*)denom)[j] = z;
}

// ---------------- fused main: glds half-tile ping-pong, 256 thr, 2 blocks/CU ----------------
// LDS (68 KB): Xs fp32 = two 32KB halves [0,32768)+[32768,65536); exs f32[64][16] [65536,69632).
// Hs/Ts (32KB) alias the tile's EARLY half after its rows are consumed; next tile's glds
// target the LATE half first, then the early half after C2 — regions ping-pong by tile parity.
// All weights hoisted to registers (legal at 2 waves/SIMD): loop has NO vmem loads except glds
// -> counted vmcnt never force-drains the prefetch. E/denom stores only cause benign over-wait.
__global__ __launch_bounds__(256, 2) void k_main(
    const float* __restrict__ X,
    const unsigned short* __restrict__ WBs1,
    const unsigned short* __restrict__ WBt1,
    const unsigned short* __restrict__ WBs2,
    const unsigned short* __restrict__ WBt2,
    const int* __restrict__ seg,
    float* __restrict__ denom,
    float* __restrict__ out) {
  __shared__ __align__(16) char U[69632];
  float* const exs = (float*)(U + 65536);

  const int tid  = threadIdx.x;
  const int lane = tid & 63;
  const int w    = tid >> 6;       // 0..3
  const int lg   = lane >> 4;
  const int ml   = lane & 15;
  const int t0   = blockIdx.x * TPB;

  // ---- hoist ALL weight fragments (held across the loop; ~104 VGPR, budget 256 @2 waves/EU)
  const unsigned short* Wb1 = (w < 2) ? WBs1 : WBt1;
  const int cbase = (w & 1) * 4;
  bf16x8 W1[4][8];
  #pragma unroll
  for (int ci = 0; ci < 4; ++ci)
    #pragma unroll
    for (int ks = 0; ks < 8; ++ks)
      W1[ci][ks] = *(const bf16x8*)(Wb1 + (size_t)(((cbase + ci) * 8 + ks) * 64 + lane) * 8);
  bf16x8 W2[4][4];
  #pragma unroll
  for (int ci = 0; ci < 4; ++ci)
    #pragma unroll
    for (int ks = 0; ks < 4; ++ks)
      W2[ci][ks] = *(const bf16x8*)(WBt2 + (size_t)(((4 * w + ci) * 4 + ks) * 64 + lane) * 8);
  bf16x8 WS2[4];
  #pragma unroll
  for (int ks = 0; ks < 4; ++ks)
    WS2[ks] = *(const bf16x8*)(WBs2 + (size_t)(ks * 64 + lane) * 8);

  int gvs[TPB];
  #pragma unroll
  for (int i = 0; i < TPB; ++i) gvs[i] = seg[(size_t)(t0 + i) * 64 + lane];

  // glds one 32-row half (32KB fp32): linear LDS dest, 16B-chunk-swizzled global source
  auto stage_half = [&](int t, int dstbase, int row0) {
    const char* gX = (const char*)X + (size_t)t * 65536 + (size_t)row0 * 1024;
    #pragma unroll
    for (int i = 0; i < 8; ++i) {
      const int lr = 8 * w + i;                     // local row 0..31 (wave-uniform)
      gld16(gX + lr * 1024 + ((lane ^ (lr & 7)) * 16), U + dstbase + lr * 1024);
    }
  };

  stage_half(t0, 0, 0);        // tile t0 rows 0-31  -> region 0
  stage_half(t0, 32768, 32);   // tile t0 rows 32-63 -> region 1

  #pragma unroll 1
  for (int it = 0; it < TPB; ++it) {
    const int ebase = (it & 1) ? 32768 : 0;   // region holding rows 0-31 of this tile
    const int lbase = 32768 - ebase;
    const int gv = gvs[it];
    const int gp = __shfl_up(gv, 1, 64);
    const unsigned long long bmask = __ballot(gv != gp) | 1ull;

    f32x4 acc[4][4];
    #pragma unroll
    for (int r = 0; r < 4; ++r)
      #pragma unroll
      for (int c = 0; c < 4; ++c) acc[r][c] = fzero4();

    // ---- Phase B, rows 0-31 (early half landed; late half may still be in flight)
    WAITBAR(8);
    #pragma unroll
    for (int ks = 0; ks < 8; ++ks) {
      bf16x8 A[2];
      #pragma unroll
      for (int r = 0; r < 2; ++r) {
        const int row = 16 * r + ml;
        const char* p = U + ebase + row * 1024;
        const int c0 = ((8 * ks + 2 * lg) ^ (row & 7)) * 16;
        const int c1 = ((8 * ks + 2 * lg + 1) ^ (row & 7)) * 16;
        A[r] = pack8v(*(const f32x4*)(p + c0), *(const f32x4*)(p + c1));
      }
      #pragma unroll
      for (int ci = 0; ci < 4; ++ci)
        #pragma unroll
        for (int r = 0; r < 2; ++r)
          acc[r][ci] = __builtin_amdgcn_mfma_f32_16x16x32_bf16(A[r], W1[ci][ks], acc[r][ci], 0, 0, 0);
    }
    // ---- Phase B, rows 32-63
    WAITBAR(0);
    #pragma unroll
    for (int ks = 0; ks < 8; ++ks) {
      bf16x8 A[2];
      #pragma unroll
      for (int r = 0; r < 2; ++r) {
        const int lr = 16 * r + ml;
        const char* p = U + lbase + lr * 1024;
        const int c0 = ((8 * ks + 2 * lg) ^ (lr & 7)) * 16;
        const int c1 = ((8 * ks + 2 * lg + 1) ^ (lr & 7)) * 16;
        A[r] = pack8v(*(const f32x4*)(p + c0), *(const f32x4*)(p + c1));
      }
      #pragma unroll
      for (int ci = 0; ci < 4; ++ci)
        #pragma unroll
        for (int r = 0; r < 2; ++r)
          acc[r + 2][ci] = __builtin_amdgcn_mfma_f32_16x16x32_bf16(A[r], W1[ci][ks], acc[r + 2][ci], 0, 0, 0);
    }
    LGKMBAR();   // all waves done reading the late half
    if (it + 1 < TPB) stage_half(t0 + it + 1, lbase, 0);   // next tile rows 0-31 -> freed late half

    // ---- B-epilogue: relu + bf16 -> Hs/Ts into the early-half region (fully consumed)
    {
      char* const dst = U + ebase + ((w < 2) ? 0 : 16384);
      #pragma unroll
      for (int ci = 0; ci < 4; ++ci) {
        const int colf = cbase + ci;
        #pragma unroll
        for (int r = 0; r < 4; ++r)
          #pragma unroll
          for (int j = 0; j < 4; ++j) {
            const int row = 16 * r + 4 * lg + j;
            const int col = 16 * colf + ml;
            float v = acc[r][ci][j];
            v = v > 0.f ? v : 0.f;
            *(unsigned short*)(dst + row * 256 + ((col * 2) ^ ((row & 7) << 4))) = f2bf(v);
          }
      }
    }
    LGKMBAR();   // Hs/Ts visible

    // ---- Phase C1: scores rows 16w..16w+15; ex -> exs + denom atomics
    {
      f32x4 sa = fzero4();
      #pragma unroll
      for (int ks = 0; ks < 4; ++ks) {
        const int row = 16 * w + ml;
        const int cb = 64 * ks + 16 * lg;
        bf16x8 A2 = *(const bf16x8*)(U + ebase + row * 256 + (cb ^ ((row & 7) << 4)));
        sa = __builtin_amdgcn_mfma_f32_16x16x32_bf16(A2, WS2[ks], sa, 0, 0, 0);
      }
      const int rowbase = 16 * w + 4 * lg;
      float ex[4]; int gs[4];
      #pragma unroll
      for (int j = 0; j < 4; ++j) {
        ex[j] = __expf(sa[j]);                     // |score| ~< 1.5: no max-subtract needed
        gs[j] = __shfl(gv, rowbase + j, 64);
        exs[(rowbase + j) * 16 + ml] = ex[j];
      }
      float accd = ex[0]; int gcur = gs[0];
      #pragma unroll
      for (int j = 1; j < 4; ++j) {
        if (gs[j] == gcur) accd += ex[j];
        else { atomicAdd(denom + (size_t)gcur * NH + ml, accd); gcur = gs[j]; accd = ex[j]; }
      }
      atomicAdd(denom + (size_t)gcur * NH + ml, accd);
    }

    // ---- Phase C2: R = T1 @ Tw2; wave w -> col-frags 4w..4w+3
    f32x4 racc[4][4];
    #pragma unroll
    for (int r = 0; r < 4; ++r)
      #pragma unroll
      for (int c = 0; c < 4; ++c) racc[r][c] = fzero4();
    #pragma unroll
    for (int ks = 0; ks < 4; ++ks) {
      bf16x8 A[4];
      #pragma unroll
      for (int r = 0; r < 4; ++r) {
        const int row = 16 * r + ml;
        const int cb = 64 * ks + 16 * lg;
        A[r] = *(const bf16x8*)(U + ebase + 16384 + row * 256 + (cb ^ ((row & 7) << 4)));
      }
      #pragma unroll
      for (int ci = 0; ci < 4; ++ci)
        #pragma unroll
        for (int r = 0; r < 4; ++r)
          racc[r][ci] = __builtin_amdgcn_mfma_f32_16x16x32_bf16(A[r], W2[ci][ks], racc[r][ci], 0, 0, 0);
    }
    LGKMBAR();   // Hs/Ts reads done; exs visible
    if (it + 1 < TPB) stage_half(t0 + it + 1, ebase, 32);  // next tile rows 32-63 -> freed early half

    // ---- Phase D: racc = relu(racc) * ex[row][4w+ci]
    #pragma unroll
    for (int r = 0; r < 4; ++r)
      #pragma unroll
      for (int j = 0; j < 4; ++j) {
        const int row = 16 * r + 4 * lg + j;
        const f32x4 e = *(const f32x4*)(exs + row * 16 + 4 * w);
        #pragma unroll
        for (int ci = 0; ci < 4; ++ci) {
          float v = racc[r][ci][j];
          v = v > 0.f ? v : 0.f;
          racc[r][ci][j] = v * e[ci];
        }
      }

    // ---- Phase E: in-register segmented column sums (rf-skip); interior store, edge atomic
    unsigned long long mm = bmask;
    while (mm) {
      const int a = __builtin_ctzll(mm);
      mm &= mm - 1;
      const int b = mm ? __builtin_ctzll(mm) : 64;
      const int g = __shfl(gv, a, 64);
      f32x4 s = fzero4();
      #pragma unroll
      for (int r = 0; r < 4; ++r) {
        if (16 * r + 15 < a || 16 * r >= b) continue;   // wave-uniform rowfrag skip
        #pragma unroll
        for (int j = 0; j < 4; ++j) {
          const int row = 16 * r + 4 * lg + j;
          const float msk = ((unsigned)(row - a) < (unsigned)(b - a)) ? 1.f : 0.f;
          #pragma unroll
          for (int ci = 0; ci < 4; ++ci) s[ci] = fmaf(msk, racc[r][ci][j], s[ci]);
        }
      }
      #pragma unroll
      for (int ci = 0; ci < 4; ++ci) {
        s[ci] += __shfl_xor(s[ci], 16, 64);
        s[ci] += __shfl_xor(s[ci], 32, 64);
      }
      const bool edge = (a == 0) || (b == 64);
      if (lane < 16) {
        float* dst = out + (size_t)g * GDIM + 64 * w + lane;
        if (edge) {
          atomicAdd(dst,      s[0]); atomicAdd(dst + 16, s[1]);
          atomicAdd(dst + 32, s[2]); atomicAdd(dst + 48, s[3]);
        } else {
          dst[0] = s[0]; dst[16] = s[1]; dst[32] = s[2]; dst[48] = s[3];
        }
      }
    }
  }
}

// ---------------- epilogue: out[g][c] /= denom[g][c/16]; empty graphs -> 0 ----------------
__global__ void k_div(float* __restrict__ out, const float* __restrict__ denom) {
  int i = blockIdx.x * 256 + threadIdx.x;
  if (i >= NG * GDIM / 4) return;
  float d = denom[(size_t)(i >> 6) * NH + ((i & 63) >> 2)];
  float r = d > 0.f ? 1.0f / d : 0.f;
  float4 v = ((float4*)out)[i];
  v.x *= r; v.y *= r; v.z *= r; v.w *= r;
  ((float4*)out)[i] = v;
}

extern "C" void kernel_launch(void* const* d_in, const int* in_sizes, int n_in,
                              void* d_out, int out_size, void* d_ws, size_t ws_size,
                              hipStream_t stream) {
  (void)in_sizes; (void)n_in; (void)out_size; (void)ws_size;
  const float* X  = (const float*)d_in[0];
  const int* seg  = (const int*)d_in[1];
  const float* s1 = (const float*)d_in[3];
  const float* s2 = (const float*)d_in[4];
  const float* t1 = (const float*)d_in[5];
  const float* t2 = (const float*)d_in[6];
  float* out = (float*)d_out;
  char* ws = (char*)d_ws;

  unsigned short* WB = (unsigned short*)ws;
  float* denom = (float*)(ws + (1 << 19));

  k_prep<<<392, 256, 0, stream>>>(s1, s2, t1, t2, WB);
  k_zero<<<13282, 256, 0, stream>>>(out, denom);
  k_main<<<NTILES / TPB, 256, 0, stream>>>(X, WB, WB + 32768, WB + 98304, WB + 65536,
                                           seg, denom, out);
  k_div<<<12500, 256, 0, stream>>>(out, denom);
}

// Round 12
// 496.012 us; speedup vs baseline: 3.9950x; 3.9950x over previous
//
#include <hip/hip_runtime.h>
#include <stdint.h>

#define VN   1000000
#define VDIM 256
#define GDIM 256
#define NH   16
#define NG   50000
#define HIDD 128
#define NTILES 15625   // VN / 64

using bf16x8 = __attribute__((ext_vector_type(8))) __bf16;
using f32x4  = __attribute__((ext_vector_type(4))) float;

__device__ __forceinline__ unsigned short f2bf(float f) {
  __bf16 h = (__bf16)f;                 // native RNE (v_cvt_pk_bf16_f32)
  return __builtin_bit_cast(unsigned short, h);
}
__device__ __forceinline__ bf16x8 pack8(float4 a, float4 b) {
  bf16x8 r;
  r[0] = (__bf16)a.x; r[1] = (__bf16)a.y; r[2] = (__bf16)a.z; r[3] = (__bf16)a.w;
  r[4] = (__bf16)b.x; r[5] = (__bf16)b.y; r[6] = (__bf16)b.z; r[7] = (__bf16)b.w;
  return r;
}
__device__ __forceinline__ f32x4 fzero4() { f32x4 z = {0.f, 0.f, 0.f, 0.f}; return z; }

// ---------------- weight prep: fp32 -> bf16 in MFMA B-fragment order ----------------
// For W[K][N]: frag element idx = ((c*(K/32)+s)*64 + lane)*8 + j  holds W[32s+8*(lane>>4)+j][16c+(lane&15)]
__global__ void k_prep(const float* __restrict__ s1, const float* __restrict__ s2,
                       const float* __restrict__ t1, const float* __restrict__ t2,
                       unsigned short* __restrict__ WB) {
  int t = blockIdx.x * 256 + threadIdx.x;
  const float* W; unsigned short* dst; int K, N, lid;
  if (t < 32768)       { W = s1; dst = WB;          K = 256; N = 128; lid = t; }
  else if (t < 65536)  { W = t1; dst = WB + 32768;  K = 256; N = 128; lid = t - 32768; }
  else if (t < 98304)  { W = t2; dst = WB + 65536;  K = 128; N = 256; lid = t - 65536; }
  else if (t < 100352) { W = s2; dst = WB + 98304;  K = 128; N = 16;  lid = t - 98304; }
  else return;
  int j = lid & 7, l = (lid >> 3) & 63, rem = lid >> 9;
  int KS = K >> 5;
  int s = rem % KS, c = rem / KS;
  int row = 32 * s + 8 * (l >> 4) + j;
  int col = 16 * c + (l & 15);
  dst[lid] = f2bf(W[row * N + col]);
}

// ---------------- zero: out [NG*GDIM] + denom [NG*NH] ----------------
__global__ void k_zero(float* __restrict__ out, float* __restrict__ denom) {
  int i = blockIdx.x * 256 + threadIdx.x;
  float4 z = make_float4(0.f, 0.f, 0.f, 0.f);
  if (i < NG * GDIM / 4) ((float4*)out)[i] = z;
  int j = i - NG * GDIM / 4;
  if (j >= 0 && j < NG * NH / 4) ((float4*)denom)[j] = z;
}

// ---------------- fused main: one 64-row tile per block (R6 structure, consolidated) ----------------
// LDS (36 KB): U[0,32768) = Xs during {A,B}; after bar2 re-used as Hs [0,16384) + Ts [16384,32768)
//              exs f32[64][16] at [32768,36864)
// 36 KB -> 4 blocks/CU (16 waves/CU): latency hidden by cross-block TLP. Streamed weights
// (no held regs across barriers except MFMA acc -> AGPRs). VGPR cap 64 via lb(256,4).
__global__ __launch_bounds__(256, 4) void k_main(
    const float* __restrict__ X,
    const unsigned short* __restrict__ WBs1,
    const unsigned short* __restrict__ WBt1,
    const unsigned short* __restrict__ WBs2,
    const unsigned short* __restrict__ WBt2,
    const int* __restrict__ seg,
    float* __restrict__ denom,
    float* __restrict__ out) {
  __shared__ __align__(16) char U[36864];
  char* const Xs = U;
  char* const Hs = U;            // aliases Xs after bar2
  char* const Ts = U + 16384;
  float* const exs = (float*)(U + 32768);

  const int tid  = threadIdx.x;
  const int lane = tid & 63;
  const int w    = tid >> 6;
  const int lg   = lane >> 4;
  const int ml   = lane & 15;
  const size_t base = (size_t)blockIdx.x * 64;

  // per-lane graph id for the tile's 64 rows (lane <-> row)
  const int gv = seg[base + lane];
  const int gp = __shfl_up(gv, 1, 64);
  const unsigned long long bmask = __ballot(gv != gp) | 1ull;  // segment-start rows

  // ---- Phase A: stage X -> bf16 LDS. 32B chunks: 2x float4 -> pack8 (cvt_pk) -> one 16B swz write
  {
    const float4* Xg = (const float4*)(X + base * VDIM);
    #pragma unroll
    for (int p = 0; p < 8; ++p) {
      const int c32 = tid + 256 * p;          // 32B fp32 chunk, 2048 total
      const int row = c32 >> 5, c8 = c32 & 31;
      float4 a = Xg[2 * c32], b = Xg[2 * c32 + 1];
      *(bf16x8*)(Xs + row * 512 + ((c8 * 16) ^ ((row & 7) << 4))) = pack8(a, b);
    }
  }
  __syncthreads();   // bar1: Xs ready

  // ---- Phase B: C1[64][256] = relu(X @ [Sw1|Tw1]); waves 0,1 -> Sw1, 2,3 -> Tw1
  {
    const unsigned short* WB = (w < 2) ? WBs1 : WBt1;
    const int cbase = (w & 1) * 4;
    f32x4 acc[4][4];
    #pragma unroll
    for (int r = 0; r < 4; ++r)
      #pragma unroll
      for (int c = 0; c < 4; ++c) acc[r][c] = fzero4();

    #pragma unroll
    for (int ks = 0; ks < 8; ++ks) {
      bf16x8 A[4];
      #pragma unroll
      for (int r = 0; r < 4; ++r) {
        const int row = 16 * r + ml;
        const int cb = 64 * ks + 16 * lg;
        A[r] = *(const bf16x8*)(Xs + row * 512 + (cb ^ ((row & 7) << 4)));
      }
      #pragma unroll
      for (int ci = 0; ci < 4; ++ci) {
        bf16x8 B = *(const bf16x8*)(WB + (size_t)(((cbase + ci) * 8 + ks) * 64 + lane) * 8);
        #pragma unroll
        for (int r = 0; r < 4; ++r)
          acc[r][ci] = __builtin_amdgcn_mfma_f32_16x16x32_bf16(A[r], B, acc[r][ci], 0, 0, 0);
      }
    }
    __syncthreads();   // bar2: all Xs reads done; U becomes Hs/Ts

    // relu + bf16 -> Hs (waves 0,1) / Ts (waves 2,3), [64][128] 256B swizzled rows
    char* const dst = (w < 2) ? Hs : Ts;
    #pragma unroll
    for (int ci = 0; ci < 4; ++ci) {
      const int colf = cbase + ci;
      #pragma unroll
      for (int r = 0; r < 4; ++r)
        #pragma unroll
        for (int j = 0; j < 4; ++j) {
          const int row = 16 * r + 4 * lg + j;
          const int col = 16 * colf + ml;
          float v = acc[r][ci][j];
          v = v > 0.f ? v : 0.f;
          *(unsigned short*)(dst + row * 256 + ((col * 2) ^ ((row & 7) << 4))) = f2bf(v);
        }
    }
  }
  __syncthreads();   // bar3: Hs/Ts complete

  // ---- Phase C1: scores = H1 @ Sw2 (wave w -> rows 16w..16w+15); ex -> exs + denom atomics
  {
    f32x4 sa = fzero4();
    #pragma unroll
    for (int ks = 0; ks < 4; ++ks) {
      const int row = 16 * w + ml;
      const int cb = 64 * ks + 16 * lg;
      bf16x8 A2 = *(const bf16x8*)(Hs + row * 256 + (cb ^ ((row & 7) << 4)));
      bf16x8 B2 = *(const bf16x8*)(WBs2 + (size_t)(ks * 64 + lane) * 8);
      sa = __builtin_amdgcn_mfma_f32_16x16x32_bf16(A2, B2, sa, 0, 0, 0);
    }
    const int rowbase = 16 * w + 4 * lg;
    float ex[4]; int gs[4];
    #pragma unroll
    for (int j = 0; j < 4; ++j) {
      ex[j] = __expf(sa[j]);                     // |score| ~< 1.5: no max-subtract needed
      gs[j] = __shfl(gv, rowbase + j, 64);
      exs[(rowbase + j) * 16 + ml] = ex[j];
    }
    float accd = ex[0]; int gcur = gs[0];
    #pragma unroll
    for (int j = 1; j < 4; ++j) {
      if (gs[j] == gcur) accd += ex[j];
      else { atomicAdd(denom + (size_t)gcur * NH + ml, accd); gcur = gs[j]; accd = ex[j]; }
    }
    atomicAdd(denom + (size_t)gcur * NH + ml, accd);
  }

  // ---- Phase C2: R = T1 @ Tw2 ; wave w -> col-frags 4w..4w+3
  f32x4 racc[4][4];
  #pragma unroll
  for (int r = 0; r < 4; ++r)
    #pragma unroll
    for (int c = 0; c < 4; ++c) racc[r][c] = fzero4();
  #pragma unroll
  for (int ks = 0; ks < 4; ++ks) {
    bf16x8 A[4];
    #pragma unroll
    for (int r = 0; r < 4; ++r) {
      const int row = 16 * r + ml;
      const int cb = 64 * ks + 16 * lg;
      A[r] = *(const bf16x8*)(Ts + row * 256 + (cb ^ ((row & 7) << 4)));
    }
    #pragma unroll
    for (int ci = 0; ci < 4; ++ci) {
      bf16x8 B = *(const bf16x8*)(WBt2 + (size_t)(((4 * w + ci) * 4 + ks) * 64 + lane) * 8);
      #pragma unroll
      for (int r = 0; r < 4; ++r)
        racc[r][ci] = __builtin_amdgcn_mfma_f32_16x16x32_bf16(A[r], B, racc[r][ci], 0, 0, 0);
    }
  }
  __syncthreads();   // bar4: exs fully written by all waves

  // ---- Phase D: racc = relu(racc) * ex[row][4w+ci]
  #pragma unroll
  for (int r = 0; r < 4; ++r)
    #pragma unroll
    for (int j = 0; j < 4; ++j) {
      const int row = 16 * r + 4 * lg + j;
      const f32x4 e = *(const f32x4*)(exs + row * 16 + 4 * w);
      #pragma unroll
      for (int ci = 0; ci < 4; ++ci) {
        float v = racc[r][ci][j];
        v = v > 0.f ? v : 0.f;
        racc[r][ci][j] = v * e[ci];
      }
    }

  // ---- Phase E: in-register segmented column sums (rf-skip); interior store, edge atomic
  unsigned long long mm = bmask;
  while (mm) {
    const int a = __builtin_ctzll(mm);
    mm &= mm - 1;
    const int b = mm ? __builtin_ctzll(mm) : 64;
    const int g = __shfl(gv, a, 64);
    f32x4 s = fzero4();
    #pragma unroll
    for (int r = 0; r < 4; ++r) {
      if (16 * r + 15 < a || 16 * r >= b) continue;   // wave-uniform rowfrag skip
      #pragma unroll
      for (int j = 0; j < 4; ++j) {
        const int row = 16 * r + 4 * lg + j;
        const float msk = ((unsigned)(row - a) < (unsigned)(b - a)) ? 1.f : 0.f;
        #pragma unroll
        for (int ci = 0; ci < 4; ++ci) s[ci] = fmaf(msk, racc[r][ci][j], s[ci]);
      }
    }
    #pragma unroll
    for (int ci = 0; ci < 4; ++ci) {
      s[ci] += __shfl_xor(s[ci], 16, 64);
      s[ci] += __shfl_xor(s[ci], 32, 64);
    }
    const bool edge = (a == 0) || (b == 64);
    if (lane < 16) {
      float* dst = out + (size_t)g * GDIM + 64 * w + lane;
      if (edge) {
        atomicAdd(dst,      s[0]); atomicAdd(dst + 16, s[1]);
        atomicAdd(dst + 32, s[2]); atomicAdd(dst + 48, s[3]);
      } else {
        dst[0] = s[0]; dst[16] = s[1]; dst[32] = s[2]; dst[48] = s[3];
      }
    }
  }
}

// ---------------- epilogue: out[g][c] /= denom[g][c/16]; empty graphs -> 0 ----------------
__global__ void k_div(float* __restrict__ out, const float* __restrict__ denom) {
  int i = blockIdx.x * 256 + threadIdx.x;
  if (i >= NG * GDIM / 4) return;
  float d = denom[(size_t)(i >> 6) * NH + ((i & 63) >> 2)];
  float r = d > 0.f ? 1.0f / d : 0.f;
  float4 v = ((float4*)out)[i];
  v.x *= r; v.y *= r; v.z *= r; v.w *= r;
  ((float4*)out)[i] = v;
}

extern "C" void kernel_launch(void* const* d_in, const int* in_sizes, int n_in,
                              void* d_out, int out_size, void* d_ws, size_t ws_size,
                              hipStream_t stream) {
  (void)in_sizes; (void)n_in; (void)out_size; (void)ws_size;
  const float* X  = (const float*)d_in[0];
  const int* seg  = (const int*)d_in[1];
  const float* s1 = (const float*)d_in[3];
  const float* s2 = (const float*)d_in[4];
  const float* t1 = (const float*)d_in[5];
  const float* t2 = (const float*)d_in[6];
  float* out = (float*)d_out;
  char* ws = (char*)d_ws;

  unsigned short* WB = (unsigned short*)ws;
  float* denom = (float*)(ws + (1 << 19));

  k_prep<<<392, 256, 0, stream>>>(s1, s2, t1, t2, WB);
  k_zero<<<13282, 256, 0, stream>>>(out, denom);
  k_main<<<NTILES, 256, 0, stream>>>(X, WB, WB + 32768, WB + 98304, WB + 65536,
                                     seg, denom, out);
  k_div<<<12500, 256, 0, stream>>>(out, denom);
}

// Round 13
// 410.081 us; speedup vs baseline: 4.8321x; 1.2095x over previous
//
#include <hip/hip_runtime.h>
#include <stdint.h>

#define VN   1000000
#define VDIM 256
#define GDIM 256
#define NH   16
#define NG   50000
#define HIDD 128
#define NTILES 15625   // VN / 64

using bf16x8 = __attribute__((ext_vector_type(8))) __bf16;
using f32x4  = __attribute__((ext_vector_type(4))) float;

__device__ __forceinline__ unsigned short f2bf(float f) {
  __bf16 h = (__bf16)f;                 // native RNE (v_cvt_pk_bf16_f32)
  return __builtin_bit_cast(unsigned short, h);
}
__device__ __forceinline__ bf16x8 pack8(float4 a, float4 b) {
  bf16x8 r;
  r[0] = (__bf16)a.x; r[1] = (__bf16)a.y; r[2] = (__bf16)a.z; r[3] = (__bf16)a.w;
  r[4] = (__bf16)b.x; r[5] = (__bf16)b.y; r[6] = (__bf16)b.z; r[7] = (__bf16)b.w;
  return r;
}
__device__ __forceinline__ f32x4 fzero4() { f32x4 z = {0.f, 0.f, 0.f, 0.f}; return z; }

// ---------------- weight prep: fp32 -> bf16 in MFMA B-fragment order ----------------
// For W[K][N]: frag element idx = ((c*(K/32)+s)*64 + lane)*8 + j  holds W[32s+8*(lane>>4)+j][16c+(lane&15)]
__global__ void k_prep(const float* __restrict__ s1, const float* __restrict__ s2,
                       const float* __restrict__ t1, const float* __restrict__ t2,
                       unsigned short* __restrict__ WB) {
  int t = blockIdx.x * 256 + threadIdx.x;
  const float* W; unsigned short* dst; int K, N, lid;
  if (t < 32768)       { W = s1; dst = WB;          K = 256; N = 128; lid = t; }
  else if (t < 65536)  { W = t1; dst = WB + 32768;  K = 256; N = 128; lid = t - 32768; }
  else if (t < 98304)  { W = t2; dst = WB + 65536;  K = 128; N = 256; lid = t - 65536; }
  else if (t < 100352) { W = s2; dst = WB + 98304;  K = 128; N = 16;  lid = t - 98304; }
  else return;
  int j = lid & 7, l = (lid >> 3) & 63, rem = lid >> 9;
  int KS = K >> 5;
  int s = rem % KS, c = rem / KS;
  int row = 32 * s + 8 * (l >> 4) + j;
  int col = 16 * c + (l & 15);
  dst[lid] = f2bf(W[row * N + col]);
}

// ---------------- zero: out [NG*GDIM] + denom [NG*NH] ----------------
__global__ void k_zero(float* __restrict__ out, float* __restrict__ denom) {
  int i = blockIdx.x * 256 + threadIdx.x;
  float4 z = make_float4(0.f, 0.f, 0.f, 0.f);
  if (i < NG * GDIM / 4) ((float4*)out)[i] = z;
  int j = i - NG * GDIM / 4;
  if (j >= 0 && j < NG * NH / 4) ((float4*)denom)[j] = z;
}

// ---------------- fused main: one 64-row tile per block, 512 thr / 8 waves ----------------
// LDS (36 KB): U[0,32768) = Xs during {A,B}; after bar2 re-used as Hs [0,16384) + Ts [16384,32768)
//              exs f32[64][16] at [32768,36864)
// vs R12: 8 waves x 2 col-frags (was 4 x 4). Per-wave weight stream HALVED (16 B-frags in B,
// 8 in C2) and lb(512,2) raises the arch-VGPR cap to 128 -> compiler can hoist B-frags
// several ks deep (the R12 stall was consume-distance-0 streams at cap 64). Nothing is
// explicitly held across barriers. 2 blocks/CU x 8 waves = 16 waves/CU (same TLP as R12).
__global__ __launch_bounds__(512, 2) void k_main(
    const float* __restrict__ X,
    const unsigned short* __restrict__ WBs1,
    const unsigned short* __restrict__ WBt1,
    const unsigned short* __restrict__ WBs2,
    const unsigned short* __restrict__ WBt2,
    const int* __restrict__ seg,
    float* __restrict__ denom,
    float* __restrict__ out) {
  __shared__ __align__(16) char U[36864];
  char* const Xs = U;
  char* const Hs = U;            // aliases Xs after bar2
  char* const Ts = U + 16384;
  float* const exs = (float*)(U + 32768);

  const int tid  = threadIdx.x;
  const int lane = tid & 63;
  const int w    = tid >> 6;     // 0..7
  const int lg   = lane >> 4;
  const int ml   = lane & 15;
  const size_t base = (size_t)blockIdx.x * 64;

  // per-lane graph id for the tile's 64 rows (lane <-> row)
  const int gv = seg[base + lane];
  const int gp = __shfl_up(gv, 1, 64);
  const unsigned long long bmask = __ballot(gv != gp) | 1ull;  // segment-start rows

  // ---- Phase A: stage X -> bf16 LDS. 32B chunks: 2x float4 -> pack8 (cvt_pk) -> one 16B swz write
  {
    const float4* Xg = (const float4*)(X + base * VDIM);
    #pragma unroll
    for (int p = 0; p < 4; ++p) {
      const int c32 = tid + 512 * p;          // 32B fp32 chunk, 2048 total
      const int row = c32 >> 5, c8 = c32 & 31;
      float4 a = Xg[2 * c32], b = Xg[2 * c32 + 1];
      *(bf16x8*)(Xs + row * 512 + ((c8 * 16) ^ ((row & 7) << 4))) = pack8(a, b);
    }
  }
  __syncthreads();   // bar1: Xs ready

  // ---- Phase B: C1[64][256] = relu(X @ [Sw1|Tw1]); waves 0-3 -> Sw1 cf{2w,2w+1}, 4-7 -> Tw1
  const unsigned short* Wb1 = (w < 4) ? WBs1 : WBt1;
  const int cw = 2 * (w & 3);
  {
    f32x4 acc[4][2];
    #pragma unroll
    for (int r = 0; r < 4; ++r) { acc[r][0] = fzero4(); acc[r][1] = fzero4(); }

    #pragma unroll
    for (int ks = 0; ks < 8; ++ks) {
      bf16x8 A[4];
      #pragma unroll
      for (int r = 0; r < 4; ++r) {
        const int row = 16 * r + ml;
        const int cb = 64 * ks + 16 * lg;
        A[r] = *(const bf16x8*)(Xs + row * 512 + (cb ^ ((row & 7) << 4)));
      }
      #pragma unroll
      for (int ci = 0; ci < 2; ++ci) {
        bf16x8 B = *(const bf16x8*)(Wb1 + (size_t)(((cw + ci) * 8 + ks) * 64 + lane) * 8);
        #pragma unroll
        for (int r = 0; r < 4; ++r)
          acc[r][ci] = __builtin_amdgcn_mfma_f32_16x16x32_bf16(A[r], B, acc[r][ci], 0, 0, 0);
      }
    }
    __syncthreads();   // bar2: all Xs reads done; U becomes Hs/Ts

    // relu + bf16 -> Hs (waves 0-3) / Ts (waves 4-7), [64][128] 256B swizzled rows
    char* const dst = (w < 4) ? Hs : Ts;
    #pragma unroll
    for (int ci = 0; ci < 2; ++ci) {
      const int colf = cw + ci;
      #pragma unroll
      for (int r = 0; r < 4; ++r)
        #pragma unroll
        for (int j = 0; j < 4; ++j) {
          const int row = 16 * r + 4 * lg + j;
          const int col = 16 * colf + ml;
          float v = acc[r][ci][j];
          v = v > 0.f ? v : 0.f;
          *(unsigned short*)(dst + row * 256 + ((col * 2) ^ ((row & 7) << 4))) = f2bf(v);
        }
    }
  }
  __syncthreads();   // bar3: Hs/Ts complete

  // ---- Phase C1 (waves 0-3): scores = H1 @ Sw2, rows 16w..16w+15; ex -> exs + denom atomics
  if (w < 4) {
    f32x4 sa = fzero4();
    #pragma unroll
    for (int ks = 0; ks < 4; ++ks) {
      const int row = 16 * w + ml;
      const int cb = 64 * ks + 16 * lg;
      bf16x8 A2 = *(const bf16x8*)(Hs + row * 256 + (cb ^ ((row & 7) << 4)));
      bf16x8 B2 = *(const bf16x8*)(WBs2 + (size_t)(ks * 64 + lane) * 8);
      sa = __builtin_amdgcn_mfma_f32_16x16x32_bf16(A2, B2, sa, 0, 0, 0);
    }
    const int rowbase = 16 * w + 4 * lg;
    float ex[4]; int gs[4];
    #pragma unroll
    for (int j = 0; j < 4; ++j) {
      ex[j] = __expf(sa[j]);                     // |score| ~< 1.5: no max-subtract needed
      gs[j] = __shfl(gv, rowbase + j, 64);
      exs[(rowbase + j) * 16 + ml] = ex[j];
    }
    float accd = ex[0]; int gcur = gs[0];
    #pragma unroll
    for (int j = 1; j < 4; ++j) {
      if (gs[j] == gcur) accd += ex[j];
      else { atomicAdd(denom + (size_t)gcur * NH + ml, accd); gcur = gs[j]; accd = ex[j]; }
    }
    atomicAdd(denom + (size_t)gcur * NH + ml, accd);
  }

  // ---- Phase C2: R = T1 @ Tw2 ; wave w -> col-frags {2w, 2w+1} of 16
  f32x4 racc[4][2];
  #pragma unroll
  for (int r = 0; r < 4; ++r) { racc[r][0] = fzero4(); racc[r][1] = fzero4(); }
  #pragma unroll
  for (int ks = 0; ks < 4; ++ks) {
    bf16x8 A[4];
    #pragma unroll
    for (int r = 0; r < 4; ++r) {
      const int row = 16 * r + ml;
      const int cb = 64 * ks + 16 * lg;
      A[r] = *(const bf16x8*)(Ts + row * 256 + (cb ^ ((row & 7) << 4)));
    }
    #pragma unroll
    for (int ci = 0; ci < 2; ++ci) {
      bf16x8 B = *(const bf16x8*)(WBt2 + (size_t)(((2 * w + ci) * 4 + ks) * 64 + lane) * 8);
      #pragma unroll
      for (int r = 0; r < 4; ++r)
        racc[r][ci] = __builtin_amdgcn_mfma_f32_16x16x32_bf16(A[r], B, racc[r][ci], 0, 0, 0);
    }
  }
  __syncthreads();   // bar4: exs fully written by all C1 waves

  // ---- Phase D: racc = relu(racc) * ex[row][2w+ci]
  #pragma unroll
  for (int r = 0; r < 4; ++r)
    #pragma unroll
    for (int j = 0; j < 4; ++j) {
      const int row = 16 * r + 4 * lg + j;
      const float2 e = *(const float2*)(exs + row * 16 + 2 * w);
      float v0 = racc[r][0][j]; v0 = v0 > 0.f ? v0 : 0.f; racc[r][0][j] = v0 * e.x;
      float v1 = racc[r][1][j]; v1 = v1 > 0.f ? v1 : 0.f; racc[r][1][j] = v1 * e.y;
    }

  // ---- Phase E: in-register segmented column sums (rf-skip); interior store, edge atomic
  unsigned long long mm = bmask;
  while (mm) {
    const int a = __builtin_ctzll(mm);
    mm &= mm - 1;
    const int b = mm ? __builtin_ctzll(mm) : 64;
    const int g = __shfl(gv, a, 64);
    float s0 = 0.f, s1 = 0.f;
    #pragma unroll
    for (int r = 0; r < 4; ++r) {
      if (16 * r + 15 < a || 16 * r >= b) continue;   // wave-uniform rowfrag skip
      #pragma unroll
      for (int j = 0; j < 4; ++j) {
        const int row = 16 * r + 4 * lg + j;
        const float msk = ((unsigned)(row - a) < (unsigned)(b - a)) ? 1.f : 0.f;
        s0 = fmaf(msk, racc[r][0][j], s0);
        s1 = fmaf(msk, racc[r][1][j], s1);
      }
    }
    s0 += __shfl_xor(s0, 16, 64); s0 += __shfl_xor(s0, 32, 64);
    s1 += __shfl_xor(s1, 16, 64); s1 += __shfl_xor(s1, 32, 64);
    const bool edge = (a == 0) || (b == 64);
    if (lane < 16) {
      float* dst = out + (size_t)g * GDIM + 32 * w + lane;
      if (edge) { atomicAdd(dst, s0); atomicAdd(dst + 16, s1); }
      else      { dst[0] = s0; dst[16] = s1; }
    }
  }
}

// ---------------- epilogue: out[g][c] /= denom[g][c/16]; empty graphs -> 0 ----------------
__global__ void k_div(float* __restrict__ out, const float* __restrict__ denom) {
  int i = blockIdx.x * 256 + threadIdx.x;
  if (i >= NG * GDIM / 4) return;
  float d = denom[(size_t)(i >> 6) * NH + ((i & 63) >> 2)];
  float r = d > 0.f ? 1.0f / d : 0.f;
  float4 v = ((float4*)out)[i];
  v.x *= r; v.y *= r; v.z *= r; v.w *= r;
  ((float4*)out)[i] = v;
}

extern "C" void kernel_launch(void* const* d_in, const int* in_sizes, int n_in,
                              void* d_out, int out_size, void* d_ws, size_t ws_size,
                              hipStream_t stream) {
  (void)in_sizes; (void)n_in; (void)out_size; (void)ws_size;
  const float* X  = (const float*)d_in[0];
  const int* seg  = (const int*)d_in[1];
  const float* s1 = (const float*)d_in[3];
  const float* s2 = (const float*)d_in[4];
  const float* t1 = (const float*)d_in[5];
  const float* t2 = (const float*)d_in[6];
  float* out = (float*)d_out;
  char* ws = (char*)d_ws;

  unsigned short* WB = (unsigned short*)ws;
  float* denom = (float*)(ws + (1 << 19));

  k_prep<<<392, 256, 0, stream>>>(s1, s2, t1, t2, WB);
  k_zero<<<13282, 256, 0, stream>>>(out, denom);
  k_main<<<NTILES, 512, 0, stream>>>(X, WB, WB + 32768, WB + 98304, WB + 65536,
                                     seg, denom, out);
  k_div<<<12500, 256, 0, stream>>>(out, denom);
}

// Round 14
// 407.770 us; speedup vs baseline: 4.8595x; 1.0057x over previous
//
#include <hip/hip_runtime.h>
#include <stdint.h>

#define VN   1000000
#define VDIM 256
#define GDIM 256
#define NH   16
#define NG   50000
#define HIDD 128
#define NTILES 15625   // VN / 64
#define NZBLK 13282    // zero blocks: ceil((NG*GDIM/4 + NG*NH/4)/256)

using bf16x8 = __attribute__((ext_vector_type(8))) __bf16;
using f32x4  = __attribute__((ext_vector_type(4))) float;

__device__ __forceinline__ unsigned short f2bf(float f) {
  __bf16 h = (__bf16)f;                 // native RNE (v_cvt_pk_bf16_f32)
  return __builtin_bit_cast(unsigned short, h);
}
__device__ __forceinline__ bf16x8 pack8(float4 a, float4 b) {
  bf16x8 r;
  r[0] = (__bf16)a.x; r[1] = (__bf16)a.y; r[2] = (__bf16)a.z; r[3] = (__bf16)a.w;
  r[4] = (__bf16)b.x; r[5] = (__bf16)b.y; r[6] = (__bf16)b.z; r[7] = (__bf16)b.w;
  return r;
}
__device__ __forceinline__ f32x4 fzero4() { f32x4 z = {0.f, 0.f, 0.f, 0.f}; return z; }

// ---------------- init: zero out+denom AND weight prep (merged, one launch) ----------------
// blocks [0, NZBLK): zero out [NG*GDIM] + denom [NG*NH]
// blocks [NZBLK, NZBLK+392): fp32 -> bf16 MFMA B-fragment reorder
// For W[K][N]: frag element idx = ((c*(K/32)+s)*64 + lane)*8 + j holds W[32s+8*(lane>>4)+j][16c+(lane&15)]
__global__ void k_init(const float* __restrict__ s1, const float* __restrict__ s2,
                       const float* __restrict__ t1, const float* __restrict__ t2,
                       unsigned short* __restrict__ WB,
                       float* __restrict__ out, float* __restrict__ denom) {
  if (blockIdx.x < NZBLK) {
    int i = blockIdx.x * 256 + threadIdx.x;
    float4 z = make_float4(0.f, 0.f, 0.f, 0.f);
    if (i < NG * GDIM / 4) ((float4*)out)[i] = z;
    int j = i - NG * GDIM / 4;
    if (j >= 0 && j < NG * NH / 4) ((float4*)denom)[j] = z;
    return;
  }
  int t = (blockIdx.x - NZBLK) * 256 + threadIdx.x;
  const float* W; unsigned short* dst; int K, N, lid;
  if (t < 32768)       { W = s1; dst = WB;          K = 256; N = 128; lid = t; }
  else if (t < 65536)  { W = t1; dst = WB + 32768;  K = 256; N = 128; lid = t - 32768; }
  else if (t < 98304)  { W = t2; dst = WB + 65536;  K = 128; N = 256; lid = t - 65536; }
  else if (t < 100352) { W = s2; dst = WB + 98304;  K = 128; N = 16;  lid = t - 98304; }
  else return;
  int j = lid & 7, l = (lid >> 3) & 63, rem = lid >> 9;
  int KS = K >> 5;
  int s = rem % KS, c = rem / KS;
  int row = 32 * s + 8 * (l >> 4) + j;
  int col = 16 * c + (l & 15);
  dst[lid] = f2bf(W[row * N + col]);
}

// ---------------- fused main: one 64-row tile per block, 512 thr / 8 waves ----------------
// LDS (68 KB): Xs [0,32768); Hs [32768,49152); Ts [49152,65536); exs f32[64][16] [65536,69632)
// vs R13: separate Hs/Ts (no Xs alias) -> bar2 deleted (3 barriers/tile). At VGPR~128 the
// occupancy limit is registers (16 waves/CU), so 68 KB LDS is free (2 x 68 <= 160).
// 8 waves x 2 col-frags: minimal per-wave weight streams; nothing held across barriers.
__global__ __launch_bounds__(512, 2) void k_main(
    const float* __restrict__ X,
    const unsigned short* __restrict__ WBs1,
    const unsigned short* __restrict__ WBt1,
    const unsigned short* __restrict__ WBs2,
    const unsigned short* __restrict__ WBt2,
    const int* __restrict__ seg,
    float* __restrict__ denom,
    float* __restrict__ out) {
  __shared__ __align__(16) char U[69632];
  char* const Xs = U;
  char* const Hs = U + 32768;
  char* const Ts = U + 49152;
  float* const exs = (float*)(U + 65536);

  const int tid  = threadIdx.x;
  const int lane = tid & 63;
  const int w    = tid >> 6;     // 0..7
  const int lg   = lane >> 4;
  const int ml   = lane & 15;
  const size_t base = (size_t)blockIdx.x * 64;

  // per-lane graph id for the tile's 64 rows (lane <-> row)
  const int gv = seg[base + lane];
  const int gp = __shfl_up(gv, 1, 64);
  const unsigned long long bmask = __ballot(gv != gp) | 1ull;  // segment-start rows

  // ---- Phase A: stage X -> bf16 LDS. 32B chunks: 2x float4 -> pack8 (cvt_pk) -> one 16B swz write
  {
    const float4* Xg = (const float4*)(X + base * VDIM);
    #pragma unroll
    for (int p = 0; p < 4; ++p) {
      const int c32 = tid + 512 * p;          // 32B fp32 chunk, 2048 total
      const int row = c32 >> 5, c8 = c32 & 31;
      float4 a = Xg[2 * c32], b = Xg[2 * c32 + 1];
      *(bf16x8*)(Xs + row * 512 + ((c8 * 16) ^ ((row & 7) << 4))) = pack8(a, b);
    }
  }
  __syncthreads();   // bar1: Xs ready

  // ---- Phase B: C1[64][256] = relu(X @ [Sw1|Tw1]); waves 0-3 -> Sw1 cf{2w,2w+1}, 4-7 -> Tw1
  const unsigned short* Wb1 = (w < 4) ? WBs1 : WBt1;
  const int cw = 2 * (w & 3);
  {
    f32x4 acc[4][2];
    #pragma unroll
    for (int r = 0; r < 4; ++r) { acc[r][0] = fzero4(); acc[r][1] = fzero4(); }

    #pragma unroll
    for (int ks = 0; ks < 8; ++ks) {
      bf16x8 A[4];
      #pragma unroll
      for (int r = 0; r < 4; ++r) {
        const int row = 16 * r + ml;
        const int cb = 64 * ks + 16 * lg;
        A[r] = *(const bf16x8*)(Xs + row * 512 + (cb ^ ((row & 7) << 4)));
      }
      #pragma unroll
      for (int ci = 0; ci < 2; ++ci) {
        bf16x8 B = *(const bf16x8*)(Wb1 + (size_t)(((cw + ci) * 8 + ks) * 64 + lane) * 8);
        #pragma unroll
        for (int r = 0; r < 4; ++r)
          acc[r][ci] = __builtin_amdgcn_mfma_f32_16x16x32_bf16(A[r], B, acc[r][ci], 0, 0, 0);
      }
    }
    // relu + bf16 -> Hs (waves 0-3) / Ts (waves 4-7): separate buffers, NO barrier needed
    char* const dst = (w < 4) ? Hs : Ts;
    #pragma unroll
    for (int ci = 0; ci < 2; ++ci) {
      const int colf = cw + ci;
      #pragma unroll
      for (int r = 0; r < 4; ++r)
        #pragma unroll
        for (int j = 0; j < 4; ++j) {
          const int row = 16 * r + 4 * lg + j;
          const int col = 16 * colf + ml;
          float v = acc[r][ci][j];
          v = v > 0.f ? v : 0.f;
          *(unsigned short*)(dst + row * 256 + ((col * 2) ^ ((row & 7) << 4))) = f2bf(v);
        }
    }
  }
  __syncthreads();   // bar2: Hs/Ts complete

  // ---- Phase C1 (waves 0-3): scores = H1 @ Sw2, rows 16w..16w+15; ex -> exs + denom atomics
  if (w < 4) {
    f32x4 sa = fzero4();
    #pragma unroll
    for (int ks = 0; ks < 4; ++ks) {
      const int row = 16 * w + ml;
      const int cb = 64 * ks + 16 * lg;
      bf16x8 A2 = *(const bf16x8*)(Hs + row * 256 + (cb ^ ((row & 7) << 4)));
      bf16x8 B2 = *(const bf16x8*)(WBs2 + (size_t)(ks * 64 + lane) * 8);
      sa = __builtin_amdgcn_mfma_f32_16x16x32_bf16(A2, B2, sa, 0, 0, 0);
    }
    const int rowbase = 16 * w + 4 * lg;
    float ex[4]; int gs[4];
    #pragma unroll
    for (int j = 0; j < 4; ++j) {
      ex[j] = __expf(sa[j]);                     // |score| ~< 1.5: no max-subtract needed
      gs[j] = __shfl(gv, rowbase + j, 64);
      exs[(rowbase + j) * 16 + ml] = ex[j];
    }
    float accd = ex[0]; int gcur = gs[0];
    #pragma unroll
    for (int j = 1; j < 4; ++j) {
      if (gs[j] == gcur) accd += ex[j];
      else { atomicAdd(denom + (size_t)gcur * NH + ml, accd); gcur = gs[j]; accd = ex[j]; }
    }
    atomicAdd(denom + (size_t)gcur * NH + ml, accd);
  }

  // ---- Phase C2: R = T1 @ Tw2 ; wave w -> col-frags {2w, 2w+1} of 16
  f32x4 racc[4][2];
  #pragma unroll
  for (int r = 0; r < 4; ++r) { racc[r][0] = fzero4(); racc[r][1] = fzero4(); }
  #pragma unroll
  for (int ks = 0; ks < 4; ++ks) {
    bf16x8 A[4];
    #pragma unroll
    for (int r = 0; r < 4; ++r) {
      const int row = 16 * r + ml;
      const int cb = 64 * ks + 16 * lg;
      A[r] = *(const bf16x8*)(Ts + row * 256 + (cb ^ ((row & 7) << 4)));
    }
    #pragma unroll
    for (int ci = 0; ci < 2; ++ci) {
      bf16x8 B = *(const bf16x8*)(WBt2 + (size_t)(((2 * w + ci) * 4 + ks) * 64 + lane) * 8);
      #pragma unroll
      for (int r = 0; r < 4; ++r)
        racc[r][ci] = __builtin_amdgcn_mfma_f32_16x16x32_bf16(A[r], B, racc[r][ci], 0, 0, 0);
    }
  }
  __syncthreads();   // bar3: exs fully written by all C1 waves

  // ---- Phase D: racc = relu(racc) * ex[row][2w+ci]
  #pragma unroll
  for (int r = 0; r < 4; ++r)
    #pragma unroll
    for (int j = 0; j < 4; ++j) {
      const int row = 16 * r + 4 * lg + j;
      const float2 e = *(const float2*)(exs + row * 16 + 2 * w);
      float v0 = racc[r][0][j]; v0 = v0 > 0.f ? v0 : 0.f; racc[r][0][j] = v0 * e.x;
      float v1 = racc[r][1][j]; v1 = v1 > 0.f ? v1 : 0.f; racc[r][1][j] = v1 * e.y;
    }

  // ---- Phase E: in-register segmented column sums (rf-skip); interior store, edge atomic
  unsigned long long mm = bmask;
  while (mm) {
    const int a = __builtin_ctzll(mm);
    mm &= mm - 1;
    const int b = mm ? __builtin_ctzll(mm) : 64;
    const int g = __shfl(gv, a, 64);
    float s0 = 0.f, s1 = 0.f;
    #pragma unroll
    for (int r = 0; r < 4; ++r) {
      if (16 * r + 15 < a || 16 * r >= b) continue;   // wave-uniform rowfrag skip
      #pragma unroll
      for (int j = 0; j < 4; ++j) {
        const int row = 16 * r + 4 * lg + j;
        const float msk = ((unsigned)(row - a) < (unsigned)(b - a)) ? 1.f : 0.f;
        s0 = fmaf(msk, racc[r][0][j], s0);
        s1 = fmaf(msk, racc[r][1][j], s1);
      }
    }
    s0 += __shfl_xor(s0, 16, 64); s0 += __shfl_xor(s0, 32, 64);
    s1 += __shfl_xor(s1, 16, 64); s1 += __shfl_xor(s1, 32, 64);
    const bool edge = (a == 0) || (b == 64);
    if (lane < 16) {
      float* dst = out + (size_t)g * GDIM + 32 * w + lane;
      if (edge) { atomicAdd(dst, s0); atomicAdd(dst + 16, s1); }
      else      { dst[0] = s0; dst[16] = s1; }
    }
  }
}

// ---------------- epilogue: out[g][c] /= denom[g][c/16]; empty graphs -> 0 ----------------
__global__ void k_div(float* __restrict__ out, const float* __restrict__ denom) {
  int i = blockIdx.x * 256 + threadIdx.x;
  if (i >= NG * GDIM / 4) return;
  float d = denom[(size_t)(i >> 6) * NH + ((i & 63) >> 2)];
  float r = d > 0.f ? 1.0f / d : 0.f;
  float4 v = ((float4*)out)[i];
  v.x *= r; v.y *= r; v.z *= r; v.w *= r;
  ((float4*)out)[i] = v;
}

extern "C" void kernel_launch(void* const* d_in, const int* in_sizes, int n_in,
                              void* d_out, int out_size, void* d_ws, size_t ws_size,
                              hipStream_t stream) {
  (void)in_sizes; (void)n_in; (void)out_size; (void)ws_size;
  const float* X  = (const float*)d_in[0];
  const int* seg  = (const int*)d_in[1];
  const float* s1 = (const float*)d_in[3];
  const float* s2 = (const float*)d_in[4];
  const float* t1 = (const float*)d_in[5];
  const float* t2 = (const float*)d_in[6];
  float* out = (float*)d_out;
  char* ws = (char*)d_ws;

  unsigned short* WB = (unsigned short*)ws;
  float* denom = (float*)(ws + (1 << 19));

  k_init<<<NZBLK + 392, 256, 0, stream>>>(s1, s2, t1, t2, WB, out, denom);
  k_main<<<NTILES, 512, 0, stream>>>(X, WB, WB + 32768, WB + 98304, WB + 65536,
                                     seg, denom, out);
  k_div<<<12500, 256, 0, stream>>>(out, denom);
}